// Round 2
// baseline (155.157 us; speedup 1.0000x reference)
//
#include <hip/hip_runtime.h>

#define C_SEG 4096
#define E_CH 16
#define NE_EDGES 16384
#define P_PIX (1024 * 1024)
#define NCHUNK 64
#define CHUNK_PIX (P_PIX / NCHUNK)   // 16384
#define SCALE 262144.0f              // 2^18 fixed point
#define INV_SCALE (1.0f / 262144.0f)
#define BIAS 4194304                 // 2^22 bias: every add is positive, per-chunk
                                     // bin occupancy is Poisson(4) (max ~25), so
                                     // sum < 25*5.8e6 << 2^31. Exact unbias in kB.

// ws layout (byte offsets):
//   0x0000000  sums_raw[16][64][4096] int  16 MB  (biased fixed-point partials)
//   0x1000000  cnt_raw[64][4096]      int   1 MB
//   0x1100000  mean[4096][16]         f32 256 KB  (normalized means)
//   0x1140000  inv_n[4096]            f32  16 KB
//   0x1144000  part[2048]             f32   8 KB

// ---------------------------------------------------------------------------
// kA: segment-sum, 16 UNIFORM groups x 64 chunks = 1024 blocks = exactly
// 4/CU (perfect balance, all co-resident, 32 waves/CU). u32 LDS atomics
// (measured-fast path from R0); the count pass is eliminated by packing
// count into the HIGH word of a u64 atomic in the g==0 group only:
//   u64 add of (1<<32) | (u32)(fix + BIAS)   -- lo never carries into hi.
// Numerically identical to separate count+sum after kB's 64-bit unbias.
// ---------------------------------------------------------------------------
__global__ __launch_bounds__(512) void kA(const float* __restrict__ emb,
                                          const int* __restrict__ seg,
                                          int* __restrict__ sums_raw,
                                          int* __restrict__ cnt_raw) {
    __shared__ unsigned long long bins64[C_SEG];  // 32 KB (g==0); g>0 alias 16 KB
    int* ib = (int*)bins64;
    const int chunk = blockIdx.x;
    const int g = blockIdx.y;
    const int t = threadIdx.x;
    const int base = chunk * CHUNK_PIX;
    const float* ec = emb + (size_t)g * P_PIX;

    if (g == 0) {
        for (int i = t; i < C_SEG; i += 512) bins64[i] = 0ull;
        __syncthreads();
        for (int it = 0; it < 8; ++it) {
            const int idx = base + (it * 512 + t) * 4;
            const int4 s4 = *(const int4*)(seg + idx);
            const float4 v = *(const float4*)(ec + idx);
            const unsigned long long ONE_HI = 1ull << 32;
            atomicAdd(&bins64[s4.x], ONE_HI | (unsigned)(__float2int_rn(v.x * SCALE) + BIAS));
            atomicAdd(&bins64[s4.y], ONE_HI | (unsigned)(__float2int_rn(v.y * SCALE) + BIAS));
            atomicAdd(&bins64[s4.z], ONE_HI | (unsigned)(__float2int_rn(v.z * SCALE) + BIAS));
            atomicAdd(&bins64[s4.w], ONE_HI | (unsigned)(__float2int_rn(v.w * SCALE) + BIAS));
        }
        __syncthreads();
        int* da = sums_raw + (size_t)chunk * C_SEG;  // ch 0
        int* cd = cnt_raw + (size_t)chunk * C_SEG;
        for (int i = t; i < C_SEG; i += 512) {
            const unsigned long long v = bins64[i];
            da[i] = (int)(unsigned)(v & 0xffffffffull);
            cd[i] = (int)(unsigned)(v >> 32);
        }
    } else {
        for (int i = t; i < C_SEG; i += 512) ib[i] = 0;
        __syncthreads();
        for (int it = 0; it < 8; ++it) {
            const int idx = base + (it * 512 + t) * 4;
            const int4 s4 = *(const int4*)(seg + idx);
            const float4 v = *(const float4*)(ec + idx);
            atomicAdd(&ib[s4.x], __float2int_rn(v.x * SCALE) + BIAS);
            atomicAdd(&ib[s4.y], __float2int_rn(v.y * SCALE) + BIAS);
            atomicAdd(&ib[s4.z], __float2int_rn(v.z * SCALE) + BIAS);
            atomicAdd(&ib[s4.w], __float2int_rn(v.w * SCALE) + BIAS);
        }
        __syncthreads();
        int* dst = sums_raw + ((size_t)g * NCHUNK + chunk) * C_SEG;
        for (int i = t; i < C_SEG; i += 512) dst[i] = ib[i];
    }
}

// ---------------------------------------------------------------------------
// kB: merge 64 chunk partials, unbias exactly (64-bit), write normalized
// MEANS and inv_n. 256 blocks x 256: c = vb>>4, segs s = (vb&15)*256+t.
// sums_raw/cnt_raw are ~17 MB, L2-resident per column; fully coalesced.
// ---------------------------------------------------------------------------
__global__ __launch_bounds__(256) void kB(const int* __restrict__ sums_raw,
                                          const int* __restrict__ cnt_raw,
                                          float* __restrict__ mean,
                                          float* __restrict__ inv_n) {
    const int vb = blockIdx.x, t = threadIdx.x;
    const int c = vb >> 4;
    const int s = (vb & 15) * 256 + t;
    const int* src = sums_raw + (size_t)c * NCHUNK * C_SEG + s;
    long long acc = 0;
    int cnt = 0;
#pragma unroll
    for (int k = 0; k < NCHUNK; ++k) {
        acc += src[(size_t)k * C_SEG];
        cnt += cnt_raw[(size_t)k * C_SEG + s];
    }
    acc -= (long long)cnt * (long long)BIAS;
    const float invn = 1.0f / fmaxf((float)cnt, 1.0f);
    mean[s * E_CH + c] = (float)acc * INV_SCALE * invn;
    if (c == 0) inv_n[s] = invn;
}

// ---------------------------------------------------------------------------
// kC: intra, 2 px/thread + 8 edges/block, 2048 blocks x 256. Live set
// ~100 VGPR (mA,mB 32 + e[16] float2 32 + misc) -> 4-5 waves/SIMD; emb
// loads coalesced at 8 B/lane. Means pre-normalized so the dot needs no
// inv_n; inv_n only scales the hinge (16 KB, L1/L2-resident gathers).
// ---------------------------------------------------------------------------
__global__ __launch_bounds__(256) void kC(const float* __restrict__ emb,
                                          const int* __restrict__ seg,
                                          const int* __restrict__ edges,
                                          const float* __restrict__ w,
                                          const float* __restrict__ mean,
                                          const float* __restrict__ inv_n,
                                          float* __restrict__ part) {
    const int b = blockIdx.x, t = threadIdx.x;
    const int q = b * 256 + t;  // pixel-pair index, 524288 total
    const int2 s2 = *(const int2*)(seg + q * 2);

    float mA[16], mB[16];
#pragma unroll
    for (int j = 0; j < 4; ++j) {
        ((float4*)mA)[j] = ((const float4*)(mean + s2.x * E_CH))[j];
        ((float4*)mB)[j] = ((const float4*)(mean + s2.y * E_CH))[j];
    }
    const float inx = inv_n[s2.x], iny = inv_n[s2.y];

    const float2* emb2 = (const float2*)emb;
    float2 e[16];
#pragma unroll
    for (int c = 0; c < 16; ++c) e[c] = emb2[(size_t)c * (P_PIX / 2) + q];

    float dx = 0.f, dy = 0.f;
#pragma unroll
    for (int c = 0; c < 16; ++c) {
        dx = fmaf(e[c].x, mA[c], dx);
        dy = fmaf(e[c].y, mB[c], dy);
    }

    float v = (fmaxf(0.5f - dx, 0.0f) * inx +
               fmaxf(0.5f - dy, 0.0f) * iny) *
              (1.0f / (float)C_SEG);

    if (t < 8) {  // 8 edges per block
        const int e2 = b * 8 + t;
        const int u = edges[e2];
        const int vv = edges[NE_EDGES + e2];
        const float4* mu = (const float4*)(mean + u * E_CH);
        const float4* mv = (const float4*)(mean + vv * E_CH);
        float dot = 0.0f;
#pragma unroll
        for (int j = 0; j < 4; ++j) {
            const float4 a = mu[j];
            const float4 bb = mv[j];
            dot = fmaf(a.x, bb.x, dot);
            dot = fmaf(a.y, bb.y, dot);
            dot = fmaf(a.z, bb.z, dot);
            dot = fmaf(a.w, bb.w, dot);
        }
        const float d = 1.0f - dot;
        v += fmaxf(1.5f - d * w[e2], 0.0f) * (1.0f / (float)NE_EDGES);
    }

    for (int o = 32; o > 0; o >>= 1) v += __shfl_down(v, o, 64);
    __shared__ float red[4];
    if ((t & 63) == 0) red[t >> 6] = v;
    __syncthreads();
    if (t == 0) part[b] = red[0] + red[1] + red[2] + red[3];
}

// ---------------------------------------------------------------------------
// kF: sum 2048 partials -> scalar.
// ---------------------------------------------------------------------------
__global__ __launch_bounds__(256) void kF(const float* __restrict__ part,
                                          float* __restrict__ out) {
    float v = 0.0f;
    for (int i = threadIdx.x; i < 2048; i += 256) v += part[i];
    for (int o = 32; o > 0; o >>= 1) v += __shfl_down(v, o, 64);
    __shared__ float red[4];
    const int t = threadIdx.x;
    if ((t & 63) == 0) red[t >> 6] = v;
    __syncthreads();
    if (t == 0) out[0] = red[0] + red[1] + red[2] + red[3];
}

extern "C" void kernel_launch(void* const* d_in, const int* in_sizes, int n_in,
                              void* d_out, int out_size, void* d_ws,
                              size_t ws_size, hipStream_t stream) {
    const float* emb = (const float*)d_in[0];      // (1,16,1024,1024) fp32
    const float* weights = (const float*)d_in[1];  // (16384,) fp32
    const int* seg = (const int*)d_in[2];          // (1,1,1024,1024) int32
    const int* edges = (const int*)d_in[3];        // (2,16384) int32
    float* out = (float*)d_out;

    char* ws = (char*)d_ws;
    int* sums_raw = (int*)(ws);
    int* cnt_raw = (int*)(ws + 0x1000000);
    float* mean = (float*)(ws + 0x1100000);
    float* invn = (float*)(ws + 0x1140000);
    float* part = (float*)(ws + 0x1144000);

    dim3 gA(NCHUNK, 16);
    kA<<<gA, 512, 0, stream>>>(emb, seg, sums_raw, cnt_raw);
    kB<<<256, 256, 0, stream>>>(sums_raw, cnt_raw, mean, invn);
    kC<<<2048, 256, 0, stream>>>(emb, seg, edges, weights, mean, invn, part);
    kF<<<1, 256, 0, stream>>>(part, out);
}

// Round 3
// 146.415 us; speedup vs baseline: 1.0597x; 1.0597x over previous
//
#include <hip/hip_runtime.h>

#define C_SEG 4096
#define E_CH 16
#define NE_EDGES 16384
#define P_PIX (1024 * 1024)
#define NCHUNK 32
#define CHUNK_PIX (P_PIX / NCHUNK)   // 32768
#define SCALE 262144.0f              // 2^18 fixed point
#define INV_SCALE (1.0f / 262144.0f)
#define BIAS 4194304                 // 2^22 bias: every add positive; per-chunk bin
                                     // occupancy Poisson(8) -> sum << 2^31. Exact
                                     // 64-bit unbias in kB.

// ws layout (byte offsets):
//   0x000000  sums_raw[16][32][4096] int   8 MB  (biased fixed-point partials)
//   0x800000  cnt_raw[32][4096]      int 512 KB
//   0x880000  mean[4096][16]         f32 256 KB  (normalized means)
//   0x8C0000  inv_n[4096]            f32  16 KB
//   0x8C4000  part[1024]             f32   4 KB

// ---------------------------------------------------------------------------
// kA: R0's measured-fast segsum (u32 LDS atomics, 16 KB bins, 512 thr,
// NCHUNK=32) with ONE change: the separate count group is eliminated by
// packing count into the HIGH word of a u64 atomic in the g==0 group only:
//   u64 add of (1<<32) | (u32)(fix + BIAS)   -- lo never carries into hi.
// Grid becomes 16 groups x 32 chunks = 512 blocks = EXACTLY 2/CU (R0's 544
// = 2.125/CU left 32 CUs running a 3rd block while 224 idled -> ~1.5x tail).
// ---------------------------------------------------------------------------
__global__ __launch_bounds__(512) void kA(const float* __restrict__ emb,
                                          const int* __restrict__ seg,
                                          int* __restrict__ sums_raw,
                                          int* __restrict__ cnt_raw) {
    __shared__ unsigned long long bins64[C_SEG];  // 32 KB (g==0); g>0 use low 16 KB
    int* ib = (int*)bins64;
    const int chunk = blockIdx.x;
    const int g = blockIdx.y;
    const int t = threadIdx.x;
    const int base = chunk * CHUNK_PIX;
    const float* ec = emb + (size_t)g * P_PIX;

    if (g == 0) {
        for (int i = t; i < C_SEG; i += 512) bins64[i] = 0ull;
        __syncthreads();
        const unsigned long long ONE_HI = 1ull << 32;
        for (int it = 0; it < 16; ++it) {
            const int idx = base + (it * 512 + t) * 4;
            const int4 s4 = *(const int4*)(seg + idx);
            const float4 v = *(const float4*)(ec + idx);
            atomicAdd(&bins64[s4.x], ONE_HI | (unsigned)(__float2int_rn(v.x * SCALE) + BIAS));
            atomicAdd(&bins64[s4.y], ONE_HI | (unsigned)(__float2int_rn(v.y * SCALE) + BIAS));
            atomicAdd(&bins64[s4.z], ONE_HI | (unsigned)(__float2int_rn(v.z * SCALE) + BIAS));
            atomicAdd(&bins64[s4.w], ONE_HI | (unsigned)(__float2int_rn(v.w * SCALE) + BIAS));
        }
        __syncthreads();
        int* da = sums_raw + (size_t)chunk * C_SEG;  // channel 0 partials
        int* cd = cnt_raw + (size_t)chunk * C_SEG;
        for (int i = t; i < C_SEG; i += 512) {
            const unsigned long long v = bins64[i];
            da[i] = (int)(unsigned)(v & 0xffffffffull);
            cd[i] = (int)(unsigned)(v >> 32);
        }
    } else {
        for (int i = t; i < C_SEG; i += 512) ib[i] = 0;
        __syncthreads();
        for (int it = 0; it < 16; ++it) {
            const int idx = base + (it * 512 + t) * 4;
            const int4 s4 = *(const int4*)(seg + idx);
            const float4 v = *(const float4*)(ec + idx);
            atomicAdd(&ib[s4.x], __float2int_rn(v.x * SCALE) + BIAS);
            atomicAdd(&ib[s4.y], __float2int_rn(v.y * SCALE) + BIAS);
            atomicAdd(&ib[s4.z], __float2int_rn(v.z * SCALE) + BIAS);
            atomicAdd(&ib[s4.w], __float2int_rn(v.w * SCALE) + BIAS);
        }
        __syncthreads();
        int* dst = sums_raw + ((size_t)g * NCHUNK + chunk) * C_SEG;
        for (int i = t; i < C_SEG; i += 512) dst[i] = ib[i];
    }
}

// ---------------------------------------------------------------------------
// kB: merge 32 chunk partials, unbias exactly (64-bit), write normalized
// MEANS and inv_n. 256 blocks x 256: c = vb>>4, segs s = (vb&15)*256+t.
// 8.5 MB coalesced reads (cnt_raw read 16x redundantly but L2-resident).
// ---------------------------------------------------------------------------
__global__ __launch_bounds__(256) void kB(const int* __restrict__ sums_raw,
                                          const int* __restrict__ cnt_raw,
                                          float* __restrict__ mean,
                                          float* __restrict__ inv_n) {
    const int vb = blockIdx.x, t = threadIdx.x;
    const int c = vb >> 4;
    const int s = (vb & 15) * 256 + t;
    const int* src = sums_raw + (size_t)c * NCHUNK * C_SEG + s;
    long long acc = 0;
    int cnt = 0;
#pragma unroll
    for (int k = 0; k < NCHUNK; ++k) {
        acc += src[(size_t)k * C_SEG];
        cnt += cnt_raw[(size_t)k * C_SEG + s];
    }
    acc -= (long long)cnt * (long long)BIAS;
    const float invn = 1.0f / fmaxf((float)cnt, 1.0f);
    mean[s * E_CH + c] = (float)acc * INV_SCALE * invn;
    if (c == 0) inv_n[s] = invn;
}

// ---------------------------------------------------------------------------
// kC: R0's measured-best intra structure: 4 px/thread + 16 edges/block,
// 1024 blocks x 256. MLP-burst: all gathers (4x4 mean rows) + 16 emb float4
// streams issued into registers before the FMA chain (~32 outstanding
// loads/wave). Means are pre-normalized so the dot needs no inv_n; inv_n
// only scales the hinge.
// ---------------------------------------------------------------------------
__global__ __launch_bounds__(256) void kC(const float* __restrict__ emb,
                                          const int* __restrict__ seg,
                                          const int* __restrict__ edges,
                                          const float* __restrict__ w,
                                          const float* __restrict__ mean,
                                          const float* __restrict__ inv_n,
                                          float* __restrict__ part) {
    const int b = blockIdx.x, t = threadIdx.x;
    const int q = b * 256 + t;  // quad index, 262144 total
    const int4 s4 = *(const int4*)(seg + q * 4);

    float mA[16], mB[16], mC[16], mD[16];
#pragma unroll
    for (int j = 0; j < 4; ++j) {
        ((float4*)mA)[j] = ((const float4*)(mean + s4.x * E_CH))[j];
        ((float4*)mB)[j] = ((const float4*)(mean + s4.y * E_CH))[j];
        ((float4*)mC)[j] = ((const float4*)(mean + s4.z * E_CH))[j];
        ((float4*)mD)[j] = ((const float4*)(mean + s4.w * E_CH))[j];
    }
    const float inx = inv_n[s4.x], iny = inv_n[s4.y];
    const float inz = inv_n[s4.z], inw = inv_n[s4.w];

    const float4* emb4 = (const float4*)emb;
    float4 e[16];
#pragma unroll
    for (int c = 0; c < 16; ++c) e[c] = emb4[(size_t)c * (P_PIX / 4) + q];

    float dx = 0.f, dy = 0.f, dz = 0.f, dw = 0.f;
#pragma unroll
    for (int c = 0; c < 16; ++c) {
        dx = fmaf(e[c].x, mA[c], dx);
        dy = fmaf(e[c].y, mB[c], dy);
        dz = fmaf(e[c].z, mC[c], dz);
        dw = fmaf(e[c].w, mD[c], dw);
    }

    float v = (fmaxf(0.5f - dx, 0.0f) * inx +
               fmaxf(0.5f - dy, 0.0f) * iny +
               fmaxf(0.5f - dz, 0.0f) * inz +
               fmaxf(0.5f - dw, 0.0f) * inw) *
              (1.0f / (float)C_SEG);

    if (t < 16) {  // 16 edges per block
        const int e2 = b * 16 + t;
        const int u = edges[e2];
        const int vv = edges[NE_EDGES + e2];
        const float4* mu = (const float4*)(mean + u * E_CH);
        const float4* mv = (const float4*)(mean + vv * E_CH);
        float dot = 0.0f;
#pragma unroll
        for (int j = 0; j < 4; ++j) {
            const float4 a = mu[j];
            const float4 bb = mv[j];
            dot = fmaf(a.x, bb.x, dot);
            dot = fmaf(a.y, bb.y, dot);
            dot = fmaf(a.z, bb.z, dot);
            dot = fmaf(a.w, bb.w, dot);
        }
        const float d = 1.0f - dot;
        v += fmaxf(1.5f - d * w[e2], 0.0f) * (1.0f / (float)NE_EDGES);
    }

    for (int o = 32; o > 0; o >>= 1) v += __shfl_down(v, o, 64);
    __shared__ float red[4];
    if ((t & 63) == 0) red[t >> 6] = v;
    __syncthreads();
    if (t == 0) part[b] = red[0] + red[1] + red[2] + red[3];
}

// ---------------------------------------------------------------------------
// kF: sum 1024 partials -> scalar.
// ---------------------------------------------------------------------------
__global__ __launch_bounds__(256) void kF(const float* __restrict__ part,
                                          float* __restrict__ out) {
    float v = 0.0f;
    for (int i = threadIdx.x; i < 1024; i += 256) v += part[i];
    for (int o = 32; o > 0; o >>= 1) v += __shfl_down(v, o, 64);
    __shared__ float red[4];
    const int t = threadIdx.x;
    if ((t & 63) == 0) red[t >> 6] = v;
    __syncthreads();
    if (t == 0) out[0] = red[0] + red[1] + red[2] + red[3];
}

extern "C" void kernel_launch(void* const* d_in, const int* in_sizes, int n_in,
                              void* d_out, int out_size, void* d_ws,
                              size_t ws_size, hipStream_t stream) {
    const float* emb = (const float*)d_in[0];      // (1,16,1024,1024) fp32
    const float* weights = (const float*)d_in[1];  // (16384,) fp32
    const int* seg = (const int*)d_in[2];          // (1,1,1024,1024) int32
    const int* edges = (const int*)d_in[3];        // (2,16384) int32
    float* out = (float*)d_out;

    char* ws = (char*)d_ws;
    int* sums_raw = (int*)(ws);
    int* cnt_raw = (int*)(ws + 0x800000);
    float* mean = (float*)(ws + 0x880000);
    float* invn = (float*)(ws + 0x8C0000);
    float* part = (float*)(ws + 0x8C4000);

    dim3 gA(NCHUNK, 16);
    kA<<<gA, 512, 0, stream>>>(emb, seg, sums_raw, cnt_raw);
    kB<<<256, 256, 0, stream>>>(sums_raw, cnt_raw, mean, invn);
    kC<<<1024, 256, 0, stream>>>(emb, seg, edges, weights, mean, invn, part);
    kF<<<1, 256, 0, stream>>>(part, out);
}

// Round 4
// 136.528 us; speedup vs baseline: 1.1364x; 1.0724x over previous
//
#include <hip/hip_runtime.h>

#define C_SEG 4096
#define E_CH 16
#define NE_EDGES 16384
#define P_PIX (1024 * 1024)
#define NCHUNK 32
#define CHUNK_PIX (P_PIX / NCHUNK)   // 32768
#define SCALE 262144.0f              // 2^18 fixed point
#define INV_SCALE (1.0f / 262144.0f)

// ws layout (byte offsets):
//   0x000000  sums_part[16][32][4096] f32    8 MB
//   0x800000  cnt_part[32][4096]      f32  512 KB
//   0x880000  msum[4096][16]          f32  256 KB   (UNnormalized sums)
//   0x8C0000  inv_n[4096]             f32   16 KB
//   0x8C4000  part[1024]              f32    4 KB
//   0x8D0000  seg16[1M]               u16    2 MB

// ---------------------------------------------------------------------------
// kP: compress seg labels (int32, <4096) to u16. 512 blocks x 256, 8 px/thr.
// 4 MB read + 2 MB write ~= 1.2 us. Pays for itself: kA re-reads seg 17x
// (68 MB as i32 -> 34 MB as u16) and kC once more (4 -> 2 MB).
// ---------------------------------------------------------------------------
__global__ __launch_bounds__(256) void kP(const int* __restrict__ seg,
                                          unsigned short* __restrict__ seg16) {
    const int i = (blockIdx.x * 256 + threadIdx.x) * 8;
    const int4 a = *(const int4*)(seg + i);
    const int4 b = *(const int4*)(seg + i + 4);
    ushort4 lo, hi;
    lo.x = (unsigned short)a.x; lo.y = (unsigned short)a.y;
    lo.z = (unsigned short)a.z; lo.w = (unsigned short)a.w;
    hi.x = (unsigned short)b.x; hi.y = (unsigned short)b.y;
    hi.z = (unsigned short)b.z; hi.w = (unsigned short)b.w;
    *(ushort4*)(seg16 + i) = lo;
    *(ushort4*)(seg16 + i + 4) = hi;
}

// ---------------------------------------------------------------------------
// kA: R0's measured-best segsum config, UNCHANGED except seg is read as u16
// (ushort4, 8 B/lane, same perfect coalescing). grid (32 chunks, 17 groups)
// x 512, 16 KB int bins, u32 LDS atomics. g==16 does counts.
// ---------------------------------------------------------------------------
__global__ __launch_bounds__(512) void kA(const float* __restrict__ emb,
                                          const unsigned short* __restrict__ seg16,
                                          float* __restrict__ sums_part,
                                          float* __restrict__ cnt_part) {
    __shared__ int bins[C_SEG];  // 16 KB
    const int chunk = blockIdx.x;
    const int g = blockIdx.y;
    const int t = threadIdx.x;
    const int base = chunk * CHUNK_PIX;

    for (int i = t; i < C_SEG; i += 512) bins[i] = 0;
    __syncthreads();

    if (g == 16) {
        for (int it = 0; it < 16; ++it) {
            const int idx = base + (it * 512 + t) * 4;
            const ushort4 s4 = *(const ushort4*)(seg16 + idx);
            atomicAdd(&bins[s4.x], 1);
            atomicAdd(&bins[s4.y], 1);
            atomicAdd(&bins[s4.z], 1);
            atomicAdd(&bins[s4.w], 1);
        }
        __syncthreads();
        float* cd = cnt_part + (size_t)chunk * C_SEG;
        for (int i = t; i < C_SEG; i += 512) cd[i] = (float)bins[i];
    } else {
        const float* ec = emb + (size_t)g * P_PIX;
        for (int it = 0; it < 16; ++it) {
            const int idx = base + (it * 512 + t) * 4;
            const ushort4 s4 = *(const ushort4*)(seg16 + idx);
            const float4 v = *(const float4*)(ec + idx);
            atomicAdd(&bins[s4.x], __float2int_rn(v.x * SCALE));
            atomicAdd(&bins[s4.y], __float2int_rn(v.y * SCALE));
            atomicAdd(&bins[s4.z], __float2int_rn(v.z * SCALE));
            atomicAdd(&bins[s4.w], __float2int_rn(v.w * SCALE));
        }
        __syncthreads();
        float* dst = sums_part + ((size_t)g * NCHUNK + chunk) * C_SEG;
        for (int i = t; i < C_SEG; i += 512)
            dst[i] = (float)bins[i] * INV_SCALE;
    }
}

// ---------------------------------------------------------------------------
// kB: R0 exact. merge chunk partials. 272 blocks x 256. vb<256: sums
// (coalesced over segs); vb in [256,272): counts -> inv_n.
// ---------------------------------------------------------------------------
__global__ __launch_bounds__(256) void kB(const float* __restrict__ sums_part,
                                          const float* __restrict__ cnt_part,
                                          float* __restrict__ msum,
                                          float* __restrict__ inv_n) {
    const int vb = blockIdx.x, t = threadIdx.x;
    if (vb < 256) {
        const int c = vb >> 4;
        const int s = (vb & 15) * 256 + t;
        const float* src = sums_part + (size_t)c * NCHUNK * C_SEG + s;
        float acc = 0.0f;
#pragma unroll
        for (int k = 0; k < NCHUNK; ++k) acc += src[(size_t)k * C_SEG];
        msum[s * E_CH + c] = acc;  // UNnormalized
    } else {
        const int s = (vb - 256) * 256 + t;
        float acc = 0.0f;
#pragma unroll
        for (int k = 0; k < NCHUNK; ++k) acc += cnt_part[(size_t)k * C_SEG + s];
        inv_n[s] = 1.0f / fmaxf(acc, 1.0f);
    }
}

// ---------------------------------------------------------------------------
// kC: R0 exact (4 px/thread MLP-burst, 16 edges/block, 1024 blocks x 256)
// except seg read as ushort4.
// ---------------------------------------------------------------------------
__global__ __launch_bounds__(256) void kC(const float* __restrict__ emb,
                                          const unsigned short* __restrict__ seg16,
                                          const int* __restrict__ edges,
                                          const float* __restrict__ w,
                                          const float* __restrict__ msum,
                                          const float* __restrict__ inv_n,
                                          float* __restrict__ part) {
    const int b = blockIdx.x, t = threadIdx.x;
    const int q = b * 256 + t;  // quad index, 262144 total
    const ushort4 s4 = *(const ushort4*)(seg16 + q * 4);

    // issue gathers (dependent only on s4)
    float mA[16], mB[16], mC[16], mD[16];
#pragma unroll
    for (int j = 0; j < 4; ++j) {
        ((float4*)mA)[j] = ((const float4*)(msum + s4.x * E_CH))[j];
        ((float4*)mB)[j] = ((const float4*)(msum + s4.y * E_CH))[j];
        ((float4*)mC)[j] = ((const float4*)(msum + s4.z * E_CH))[j];
        ((float4*)mD)[j] = ((const float4*)(msum + s4.w * E_CH))[j];
    }
    const float inx = inv_n[s4.x], iny = inv_n[s4.y];
    const float inz = inv_n[s4.z], inw = inv_n[s4.w];

    // burst-load all 16 emb quads (64 VGPRs of results in flight)
    const float4* emb4 = (const float4*)emb;
    float4 e[16];
#pragma unroll
    for (int c = 0; c < 16; ++c) e[c] = emb4[(size_t)c * (P_PIX / 4) + q];

    float dx = 0.f, dy = 0.f, dz = 0.f, dw = 0.f;
#pragma unroll
    for (int c = 0; c < 16; ++c) {
        dx = fmaf(e[c].x, mA[c], dx);
        dy = fmaf(e[c].y, mB[c], dy);
        dz = fmaf(e[c].z, mC[c], dz);
        dw = fmaf(e[c].w, mD[c], dw);
    }

    float v = (fmaxf(0.5f - inx * dx, 0.0f) * inx +
               fmaxf(0.5f - iny * dy, 0.0f) * iny +
               fmaxf(0.5f - inz * dz, 0.0f) * inz +
               fmaxf(0.5f - inw * dw, 0.0f) * inw) *
              (1.0f / (float)C_SEG);

    if (t < 16) {  // 16 edges per block
        const int e2 = b * 16 + t;
        const int u = edges[e2];
        const int vv = edges[NE_EDGES + e2];
        const float4* mu = (const float4*)(msum + u * E_CH);
        const float4* mv = (const float4*)(msum + vv * E_CH);
        float dot = 0.0f;
#pragma unroll
        for (int j = 0; j < 4; ++j) {
            const float4 a = mu[j];
            const float4 bb = mv[j];
            dot = fmaf(a.x, bb.x, dot);
            dot = fmaf(a.y, bb.y, dot);
            dot = fmaf(a.z, bb.z, dot);
            dot = fmaf(a.w, bb.w, dot);
        }
        const float d = 1.0f - inv_n[u] * inv_n[vv] * dot;
        v += fmaxf(1.5f - d * w[e2], 0.0f) * (1.0f / (float)NE_EDGES);
    }

    for (int o = 32; o > 0; o >>= 1) v += __shfl_down(v, o, 64);
    __shared__ float red[4];
    if ((t & 63) == 0) red[t >> 6] = v;
    __syncthreads();
    if (t == 0) part[b] = red[0] + red[1] + red[2] + red[3];
}

// ---------------------------------------------------------------------------
// kF: sum 1024 partials -> scalar.
// ---------------------------------------------------------------------------
__global__ __launch_bounds__(256) void kF(const float* __restrict__ part,
                                          float* __restrict__ out) {
    float v = 0.0f;
    for (int i = threadIdx.x; i < 1024; i += 256) v += part[i];
    for (int o = 32; o > 0; o >>= 1) v += __shfl_down(v, o, 64);
    __shared__ float red[4];
    const int t = threadIdx.x;
    if ((t & 63) == 0) red[t >> 6] = v;
    __syncthreads();
    if (t == 0) out[0] = red[0] + red[1] + red[2] + red[3];
}

extern "C" void kernel_launch(void* const* d_in, const int* in_sizes, int n_in,
                              void* d_out, int out_size, void* d_ws,
                              size_t ws_size, hipStream_t stream) {
    const float* emb = (const float*)d_in[0];      // (1,16,1024,1024) fp32
    const float* weights = (const float*)d_in[1];  // (16384,) fp32
    const int* seg = (const int*)d_in[2];          // (1,1,1024,1024) int32
    const int* edges = (const int*)d_in[3];        // (2,16384) int32
    float* out = (float*)d_out;

    char* ws = (char*)d_ws;
    float* sums_part = (float*)(ws);
    float* cnt_part = (float*)(ws + 0x800000);
    float* msum = (float*)(ws + 0x880000);
    float* invn = (float*)(ws + 0x8C0000);
    float* part = (float*)(ws + 0x8C4000);
    unsigned short* seg16 = (unsigned short*)(ws + 0x8D0000);

    kP<<<512, 256, 0, stream>>>(seg, seg16);
    dim3 gA(NCHUNK, 17);
    kA<<<gA, 512, 0, stream>>>(emb, seg16, sums_part, cnt_part);
    kB<<<272, 256, 0, stream>>>(sums_part, cnt_part, msum, invn);
    kC<<<1024, 256, 0, stream>>>(emb, seg16, edges, weights, msum, invn, part);
    kF<<<1, 256, 0, stream>>>(part, out);
}